// Round 8
// baseline (233.179 us; speedup 1.0000x reference)
//
#include <hip/hip_runtime.h>

#define HIDDEN 64
#define HALFD  32
#define VOCAB  64
#define BATCH  256
#define SEQLEN 2048

#define RLF(v, sl) __int_as_float(__builtin_amdgcn_readlane(__float_as_int(v), (sl)))
#define RLI(v, sl) __builtin_amdgcn_readlane((v), (sl))

// ---------------------------------------------------------------------------
// Kernel 1: per-token vocab tables (unchanged).
//   ws[0    ..2047]  ks_voc [64][32]  (normalized hs)
//   ws[2048 ..4095]  ke_voc [64][32]  (normalized he)
//   ws[4096 ..6143]  vs_voc [64][32]  (raw hs)
//   ws[6144 ..8191]  ve_voc [64][32]  (raw he)
//   ws[8192 ..16383] Gs,Ge [2][64][64]
// ---------------------------------------------------------------------------
__global__ __launch_bounds__(64) void vocab_kernel(
    const float* __restrict__ embed, const float* __restrict__ W1, const float* __restrict__ b1,
    const float* __restrict__ W2, const float* __restrict__ b2,
    const float* __restrict__ ln_g, const float* __restrict__ ln_b,
    const float* __restrict__ Ws, const float* __restrict__ bs,
    const float* __restrict__ We, const float* __restrict__ be,
    float* __restrict__ ws)
{
    const int v = blockIdx.x;
    const int tid = threadIdx.x;

    __shared__ float e_s[64];
    __shared__ float a1_s[128];
    __shared__ float h_s[64];

    e_s[tid] = embed[v * 64 + tid];
    __syncthreads();

    float acc0 = b1[tid], acc1 = b1[tid + 64];
    #pragma unroll 8
    for (int m = 0; m < 64; ++m) {
        float ev = e_s[m];
        acc0 = fmaf(ev, W1[tid * 64 + m], acc0);
        acc1 = fmaf(ev, W1[(tid + 64) * 64 + m], acc1);
    }
    a1_s[tid]      = fmaxf(acc0, 0.0f);
    a1_s[tid + 64] = fmaxf(acc1, 0.0f);
    __syncthreads();

    float ff = b2[tid];
    #pragma unroll 8
    for (int m = 0; m < 128; ++m) ff = fmaf(a1_s[m], W2[tid * 128 + m], ff);
    float x = e_s[tid] + ff;

    float s = x, s2 = x * x;
    #pragma unroll
    for (int off = 32; off >= 1; off >>= 1) {
        s  += __shfl_xor(s,  off, 64);
        s2 += __shfl_xor(s2, off, 64);
    }
    float mu  = s * (1.0f / 64.0f);
    float var = s2 * (1.0f / 64.0f) - mu * mu;
    float hval = (x - mu) * rsqrtf(var + 1e-5f) * ln_g[tid] + ln_b[tid];
    h_s[tid] = hval;
    __syncthreads();

    const int j = tid & 31;
    const bool is_s = tid < 32;
    const float* W = is_s ? Ws : We;
    float acc = is_s ? bs[j] : be[j];
    #pragma unroll 8
    for (int m = 0; m < 64; ++m) acc = fmaf(h_s[m], W[j * 64 + m], acc);

    float n2 = acc * acc;
    #pragma unroll
    for (int off = 16; off >= 1; off >>= 1) n2 += __shfl_xor(n2, off, 64);
    float norm = sqrtf(n2);
    float kn = acc / fmaxf(norm, 1e-12f);

    const int base = v * 32 + j;
    if (is_s) { ws[base]        = kn; ws[4096 + base] = acc; }
    else      { ws[2048 + base] = kn; ws[6144 + base] = acc; }
}

// ---------------------------------------------------------------------------
// Kernel 1b: Gram tables G_w[a][b] = k_w[a].k_w[b], [64][64] in ws (unchanged).
// ---------------------------------------------------------------------------
__global__ __launch_bounds__(256) void gram_kernel(float* __restrict__ ws)
{
    const int w = blockIdx.x;
    const int tid = threadIdx.x;
    __shared__ float k_s[2048];
    const float* kb = ws + w * 2048;
    for (int i = tid; i < 2048; i += 256) k_s[i] = kb[i];
    __syncthreads();
    const int a  = tid >> 2;
    const int b0 = (tid & 3) << 4;
    float* Gw = ws + 8192 + w * 4096 + a * 64;
    for (int bb = 0; bb < 16; ++bb) {
        const int bcol = b0 + bb;
        float acc = 0.f;
        #pragma unroll
        for (int m = 0; m < 32; ++m) acc = fmaf(k_s[a * 32 + m], k_s[bcol * 32 + m], acc);
        Gw[bcol] = acc;
    }
}

// ---------------------------------------------------------------------------
// Kernel 2: Gram-space backward sweep, SINGLE-BPERMUTE chunks.
// R7 post-mortem: the loop was DS-pipe-bound (18 DS ops/chunk/wave, two waves
// sharing one LDS pipe). This version keeps R7's exact algebra but:
//  - ONE ds_bpermute per chunk: lane j gathers u[tok_j] itself (per-lane
//    index shfl), then 8 v_readlane broadcasts (VALU pipe).
//  - G rows + token reads come from GLOBAL (VMEM pipe, L1/L2-resident,
//    prefetched 1-2 chunks ahead) instead of LDS.
//  - No bulk LDS staging at all (loop LDS use = the bpermute only).
// ---------------------------------------------------------------------------
__global__ __launch_bounds__(128) void scan_kernel(
    const int* __restrict__ seq, const float* __restrict__ ws,
    const float* __restrict__ Wrp, const float* __restrict__ brp,
    const float* __restrict__ Wo, const float* __restrict__ bo,
    float* __restrict__ out)
{
    const int b    = blockIdx.x;
    const int tid  = threadIdx.x;        // 0..127
    const int w    = tid >> 6;           // wave: 0 = s-branch, 1 = e-branch
    const int lane = tid & 63;
    const int l7   = lane & 7;
    const bool is_e = (w == 1);

    __shared__ float wacc_s[2][64];
    __shared__ float r_s[64];
    __shared__ float t1_s[64];

    const int*   sq = seq + b * SEQLEN;
    const float* Gg = ws + 8192 + w * 4096;     // [64][64] Gram, global (L1/L2)

    const float invL = 1.0f / (float)SEQLEN;

    // --- prologue ---
    // chunk 255 tokens, lane-indexed (lane j holds tok[2040+j], replicated /8)
    int tokvC = sq[2040 + l7];
    int tk0 = RLI(tokvC, 0), tk1 = RLI(tokvC, 1), tk2 = RLI(tokvC, 2), tk3 = RLI(tokvC, 3);
    int tk4 = RLI(tokvC, 4), tk5 = RLI(tokvC, 5), tk6 = RLI(tokvC, 6), tk7 = RLI(tokvC, 7);

    // G rows for chunk 255
    float grow0 = Gg[tk0 * 64 + lane], grow1 = Gg[tk1 * 64 + lane];
    float grow2 = Gg[tk2 * 64 + lane], grow3 = Gg[tk3 * 64 + lane];
    float grow4 = Gg[tk4 * 64 + lane], grow5 = Gg[tk5 * 64 + lane];
    float grow6 = Gg[tk6 * 64 + lane], grow7 = Gg[tk7 * 64 + lane];

    // tokens for chunk 254 (lane-indexed, in flight)
    int tokvN = sq[2032 + l7];

    // u init: query token IS position 2047 = tk7 of chunk 255
    float u = Gg[tk7 * 64 + lane];
    float waccv = 0.0f;

    for (int c = 255; c >= 0; --c) {
        // ONE bpermute: lane j gets u[tok_{8c+j}]
        float bp = __shfl(u, tokvC, 64);

        // next-chunk tokens -> SGPRs; issue next G rows + chunk c-2 tokens
        int nk0 = RLI(tokvN, 0), nk1 = RLI(tokvN, 1), nk2 = RLI(tokvN, 2), nk3 = RLI(tokvN, 3);
        int nk4 = RLI(tokvN, 4), nk5 = RLI(tokvN, 5), nk6 = RLI(tokvN, 6), nk7 = RLI(tokvN, 7);
        float gn0 = Gg[nk0 * 64 + lane], gn1 = Gg[nk1 * 64 + lane];
        float gn2 = Gg[nk2 * 64 + lane], gn3 = Gg[nk3 * 64 + lane];
        float gn4 = Gg[nk4 * 64 + lane], gn5 = Gg[nk5 * 64 + lane];
        float gn6 = Gg[nk6 * 64 + lane], gn7 = Gg[nk7 * 64 + lane];
        int cm2 = (c >= 2) ? (c - 2) : 0;
        int tokv2 = sq[cm2 * 8 + l7];

        // g_jm from resident row registers (VALU, zero DS)
        float g01 = RLF(grow0, tk1), g02 = RLF(grow0, tk2), g03 = RLF(grow0, tk3);
        float g04 = RLF(grow0, tk4), g05 = RLF(grow0, tk5), g06 = RLF(grow0, tk6), g07 = RLF(grow0, tk7);
        float g12 = RLF(grow1, tk2), g13 = RLF(grow1, tk3), g14 = RLF(grow1, tk4);
        float g15 = RLF(grow1, tk5), g16 = RLF(grow1, tk6), g17 = RLF(grow1, tk7);
        float g23 = RLF(grow2, tk3), g24 = RLF(grow2, tk4), g25 = RLF(grow2, tk5);
        float g26 = RLF(grow2, tk6), g27 = RLF(grow2, tk7);
        float g34 = RLF(grow3, tk4), g35 = RLF(grow3, tk5), g36 = RLF(grow3, tk6), g37 = RLF(grow3, tk7);
        float g45 = RLF(grow4, tk5), g46 = RLF(grow4, tk6), g47 = RLF(grow4, tk7);
        float g56 = RLF(grow5, tk6), g57 = RLF(grow5, tk7);
        float g67 = RLF(grow6, tk7);

        // broadcast t_j to all lanes (VALU readlane, not bpermute)
        float t0 = RLF(bp, 0), t1 = RLF(bp, 1), t2 = RLF(bp, 2), t3 = RLF(bp, 3);
        float t4 = RLF(bp, 4), t5 = RLF(bp, 5), t6 = RLF(bp, 6), t7 = RLF(bp, 7);

        // per-step factors (position 8c+7 of chunk 255 is the query: f7 = 0)
        float fb = (float)(8 * c + 1) * invL;
        float f0 = is_e ? fb            : 1.0f;
        float f1 = is_e ? fb +     invL : 1.0f;
        float f2 = is_e ? fb + 2 * invL : 1.0f;
        float f3 = is_e ? fb + 3 * invL : 1.0f;
        float f4 = is_e ? fb + 4 * invL : 1.0f;
        float f5 = is_e ? fb + 5 * invL : 1.0f;
        float f6 = is_e ? fb + 6 * invL : 1.0f;
        float f7 = (c == 255) ? 0.0f : (is_e ? fb + 7 * invL : 1.0f);

        // triangular WY adjoint solve (all lanes redundantly) — verbatim R7
        float s7 = f7 * t7;
        float s6 = f6 * (t6 - g67 * s7);
        float s5 = f5 * ((t5 - g57 * s7) - g56 * s6);
        float s4 = f4 * (((t4 - g47 * s7) - g46 * s6) - g45 * s5);
        float s3 = f3 * ((((t3 - g37 * s7) - g36 * s6) - g35 * s5) - g34 * s4);
        float s2 = f2 * (((((t2 - g27 * s7) - g26 * s6) - g25 * s5) - g24 * s4) - g23 * s3);
        float s1 = f1 * ((((((t1 - g17 * s7) - g16 * s6) - g15 * s5) - g14 * s4) - g13 * s3) - g12 * s2);
        float s0 = f0 * (((((((t0 - g07 * s7) - g06 * s6) - g05 * s5) - g04 * s4) - g03 * s3) - g02 * s2) - g01 * s1);

        // u[a] -= sum_j s_j * G[tok_j][a]
        {
            float A = fmaf(grow0, s0, fmaf(grow1, s1, fmaf(grow2, s2, grow3 * s3)));
            float B = fmaf(grow4, s4, fmaf(grow5, s5, fmaf(grow6, s6, grow7 * s7)));
            u -= (A + B);
        }

        // wacc[tok_j] += s_j  (lane = token)
        waccv += (lane == tk0) ? s0 : 0.0f;
        waccv += (lane == tk1) ? s1 : 0.0f;
        waccv += (lane == tk2) ? s2 : 0.0f;
        waccv += (lane == tk3) ? s3 : 0.0f;
        waccv += (lane == tk4) ? s4 : 0.0f;
        waccv += (lane == tk5) ? s5 : 0.0f;
        waccv += (lane == tk6) ? s6 : 0.0f;
        waccv += (lane == tk7) ? s7 : 0.0f;

        // rotate pipeline
        tk0 = nk0; tk1 = nk1; tk2 = nk2; tk3 = nk3;
        tk4 = nk4; tk5 = nk5; tk6 = nk6; tk7 = nk7;
        grow0 = gn0; grow1 = gn1; grow2 = gn2; grow3 = gn3;
        grow4 = gn4; grow5 = gn5; grow6 = gn6; grow7 = gn7;
        tokvC = tokvN; tokvN = tokv2;
    }

    wacc_s[w][lane] = waccv;
    __syncthreads();

    // r[w2][rho] = sum_tok wacc[w2][tok] * v[w2][tok][rho]  (v from global ws)
    if (tid < 64) {
        const int w2  = tid >> 5;
        const int rho = tid & 31;
        const float* vv = ws + 4096 + w2 * 2048;
        const float* wa = &wacc_s[w2][0];
        float acc = 0.0f;
        #pragma unroll 8
        for (int tok = 0; tok < 64; ++tok) acc = fmaf(wa[tok], vv[tok * 32 + rho], acc);
        r_s[tid] = acc;
    }
    __syncthreads();

    // out = (r @ Wrp.T + brp) @ Wo.T + bo
    if (tid < 64) {
        float acc = brp[tid];
        #pragma unroll 8
        for (int m = 0; m < 64; ++m) acc = fmaf(Wrp[tid * 64 + m], r_s[m], acc);
        t1_s[tid] = acc;
    }
    __syncthreads();
    if (tid < 64) {
        float acc = bo[tid];
        #pragma unroll 8
        for (int m = 0; m < 64; ++m) acc = fmaf(Wo[tid * 64 + m], t1_s[m], acc);
        out[b * 64 + tid] = acc;
    }
}

extern "C" void kernel_launch(void* const* d_in, const int* in_sizes, int n_in,
                              void* d_out, int out_size, void* d_ws, size_t ws_size,
                              hipStream_t stream)
{
    const int*   seq   = (const int*)  d_in[0];
    const float* embed = (const float*)d_in[1];
    const float* W1    = (const float*)d_in[2];
    const float* b1    = (const float*)d_in[3];
    const float* W2    = (const float*)d_in[4];
    const float* b2    = (const float*)d_in[5];
    const float* ln_g  = (const float*)d_in[6];
    const float* ln_b  = (const float*)d_in[7];
    const float* Ws    = (const float*)d_in[8];
    const float* bs    = (const float*)d_in[9];
    const float* We    = (const float*)d_in[10];
    const float* be    = (const float*)d_in[11];
    const float* Wrp   = (const float*)d_in[12];
    const float* brp   = (const float*)d_in[13];
    const float* Wo    = (const float*)d_in[14];
    const float* bo    = (const float*)d_in[15];
    float* ws  = (float*)d_ws;
    float* out = (float*)d_out;

    hipLaunchKernelGGL(vocab_kernel, dim3(VOCAB), dim3(64), 0, stream,
                       embed, W1, b1, W2, b2, ln_g, ln_b, Ws, bs, We, be, ws);
    hipLaunchKernelGGL(gram_kernel, dim3(2), dim3(256), 0, stream, ws);
    hipLaunchKernelGGL(scan_kernel, dim3(BATCH), dim3(128), 0, stream,
                       seq, ws, Wrp, brp, Wo, bo, out);
}

// Round 9
// 211.088 us; speedup vs baseline: 1.1047x; 1.1047x over previous
//
#include <hip/hip_runtime.h>

#define HIDDEN 64
#define HALFD  32
#define VOCAB  64
#define BATCH  256
#define SEQLEN 2048

#define RLF(v, sl) __int_as_float(__builtin_amdgcn_readlane(__float_as_int(v), (sl)))
#define RLI(v, sl) __builtin_amdgcn_readlane((v), (sl))
#define GIX(j,m) (((j)==0?0:(j)==1?7:(j)==2?13:(j)==3?18:(j)==4?22:(j)==5?25:27) + (m) - (j) - 1)
#define OM(m) (((m)*((m)+1))>>1)

// ---------------------------------------------------------------------------
// Kernel 1: per-token vocab tables (unchanged).
//   ws[0    ..2047]  ks_voc [64][32]  (normalized hs)
//   ws[2048 ..4095]  ke_voc [64][32]  (normalized he)
//   ws[4096 ..6143]  vs_voc [64][32]  (raw hs)
//   ws[6144 ..8191]  ve_voc [64][32]  (raw he)
//   ws[8192 ..16383] Gs,Ge [2][64][64]
// ---------------------------------------------------------------------------
__global__ __launch_bounds__(64) void vocab_kernel(
    const float* __restrict__ embed, const float* __restrict__ W1, const float* __restrict__ b1,
    const float* __restrict__ W2, const float* __restrict__ b2,
    const float* __restrict__ ln_g, const float* __restrict__ ln_b,
    const float* __restrict__ Ws, const float* __restrict__ bs,
    const float* __restrict__ We, const float* __restrict__ be,
    float* __restrict__ ws)
{
    const int v = blockIdx.x;
    const int tid = threadIdx.x;

    __shared__ float e_s[64];
    __shared__ float a1_s[128];
    __shared__ float h_s[64];

    e_s[tid] = embed[v * 64 + tid];
    __syncthreads();

    float acc0 = b1[tid], acc1 = b1[tid + 64];
    #pragma unroll 8
    for (int m = 0; m < 64; ++m) {
        float ev = e_s[m];
        acc0 = fmaf(ev, W1[tid * 64 + m], acc0);
        acc1 = fmaf(ev, W1[(tid + 64) * 64 + m], acc1);
    }
    a1_s[tid]      = fmaxf(acc0, 0.0f);
    a1_s[tid + 64] = fmaxf(acc1, 0.0f);
    __syncthreads();

    float ff = b2[tid];
    #pragma unroll 8
    for (int m = 0; m < 128; ++m) ff = fmaf(a1_s[m], W2[tid * 128 + m], ff);
    float x = e_s[tid] + ff;

    float s = x, s2 = x * x;
    #pragma unroll
    for (int off = 32; off >= 1; off >>= 1) {
        s  += __shfl_xor(s,  off, 64);
        s2 += __shfl_xor(s2, off, 64);
    }
    float mu  = s * (1.0f / 64.0f);
    float var = s2 * (1.0f / 64.0f) - mu * mu;
    float hval = (x - mu) * rsqrtf(var + 1e-5f) * ln_g[tid] + ln_b[tid];
    h_s[tid] = hval;
    __syncthreads();

    const int j = tid & 31;
    const bool is_s = tid < 32;
    const float* W = is_s ? Ws : We;
    float acc = is_s ? bs[j] : be[j];
    #pragma unroll 8
    for (int m = 0; m < 64; ++m) acc = fmaf(h_s[m], W[j * 64 + m], acc);

    float n2 = acc * acc;
    #pragma unroll
    for (int off = 16; off >= 1; off >>= 1) n2 += __shfl_xor(n2, off, 64);
    float norm = sqrtf(n2);
    float kn = acc / fmaxf(norm, 1e-12f);

    const int base = v * 32 + j;
    if (is_s) { ws[base]        = kn; ws[4096 + base] = acc; }
    else      { ws[2048 + base] = kn; ws[6144 + base] = acc; }
}

// ---------------------------------------------------------------------------
// Kernel 1b: Gram tables G_w[a][b] = k_w[a].k_w[b], [64][64] in ws (unchanged).
// ---------------------------------------------------------------------------
__global__ __launch_bounds__(256) void gram_kernel(float* __restrict__ ws)
{
    const int w = blockIdx.x;
    const int tid = threadIdx.x;
    __shared__ float k_s[2048];
    const float* kb = ws + w * 2048;
    for (int i = tid; i < 2048; i += 256) k_s[i] = kb[i];
    __syncthreads();
    const int a  = tid >> 2;
    const int b0 = (tid & 3) << 4;
    float* Gw = ws + 8192 + w * 4096 + a * 64;
    for (int bb = 0; bb < 16; ++bb) {
        const int bcol = b0 + bb;
        float acc = 0.f;
        #pragma unroll
        for (int m = 0; m < 32; ++m) acc = fmaf(k_s[a * 32 + m], k_s[bcol * 32 + m], acc);
        Gw[bcol] = acc;
    }
}

// ---------------------------------------------------------------------------
// Kernel 2: Gram-space backward sweep with PRECOMPUTED per-chunk solve
// matrices. The triangular WY solve s = f*(t - U s) is linear: s = W t with
// 8x8 upper-tri W depending only on (tokens, chunk, branch). Prologue builds
// all 256 W-packs per branch (lanes parallel over chunks, 4 chunks/lane) into
// LDS; the serial loop is then: 1 bpermute -> 8 t-readlanes -> 36 independent
// FMAs (depth<=4) -> u-update -> wacc. No g-readlanes, no f-selects in loop.
// ---------------------------------------------------------------------------
struct Chunk {
    int   tokv;      // lane-vector: tok[c*8 + (lane&7)]
    int   tk[8];     // uniform tokens of this chunk
    float grow[8];   // G[tok_j][lane]
    float W[36];     // packed upper-tri solve matrix, col-major: W[OM(m)+j]
};

__global__ __launch_bounds__(128) void scan_kernel(
    const int* __restrict__ seq, const float* __restrict__ ws,
    const float* __restrict__ Wrp, const float* __restrict__ brp,
    const float* __restrict__ Wo, const float* __restrict__ bo,
    float* __restrict__ out)
{
    const int b    = blockIdx.x;
    const int tid  = threadIdx.x;        // 0..127
    const int w    = tid >> 6;           // wave: 0 = s-branch, 1 = e-branch
    const int lane = tid & 63;
    const int l7   = lane & 7;
    const bool is_e = (w == 1);

    __shared__ __align__(16) float Wtab[2 * 256 * 36];   // 72 KB solve packs
    __shared__ __align__(16) int   toklds[SEQLEN];       // 8 KB
    __shared__ float wacc_s[2][64];
    __shared__ float r_s[64];
    __shared__ float t1_s[64];

    const float* Gg     = ws + 8192 + w * 4096;          // [64][64] global
    float*       Wtab_w = Wtab + w * (256 * 36);

    // ---- stage token sequence ----
    {
        const int4* sq4 = (const int4*)(seq + b * SEQLEN);
        int4* tl = (int4*)toklds;
        #pragma unroll
        for (int i = 0; i < 4; ++i) tl[tid + i * 128] = sq4[tid + i * 128];
    }
    __syncthreads();

    // ---- precompute W packs: lanes parallel over chunks (4 per lane) ----
    {
        const float invL = 1.0f / (float)SEQLEN;
        #pragma unroll
        for (int qq = 0; qq < 4; ++qq) {
            const int c = lane + (qq << 6);
            int tj[8];
            #pragma unroll
            for (int j = 0; j < 8; ++j) tj[j] = toklds[c * 8 + j];

            float f[8];
            float fb = (float)(8 * c + 1) * invL;
            #pragma unroll
            for (int j = 0; j < 8; ++j) f[j] = is_e ? (fb + (float)j * invL) : 1.0f;
            if (c == 255) f[7] = 0.0f;    // position 2047 is the query, not a write

            float g[28];
            #pragma unroll
            for (int j = 0; j < 7; ++j)
                #pragma unroll
                for (int m = j + 1; m < 8; ++m) g[GIX(j, m)] = Gg[tj[j] * 64 + tj[m]];

            // W columns by basis recurrence: col m = s-vector for t = e_m
            float Wp[36];
            #pragma unroll
            for (int m = 0; m < 8; ++m) {
                float col[8];
                col[m] = f[m];
                #pragma unroll
                for (int j = 6; j >= 0; --j) {
                    if (j < m) {
                        float acc = 0.0f;
                        #pragma unroll
                        for (int p = 1; p < 8; ++p)
                            if (p > j && p <= m) acc = fmaf(g[GIX(j, p)], col[p], acc);
                        col[j] = -f[j] * acc;
                    }
                }
                #pragma unroll
                for (int j = 0; j < 8; ++j)
                    if (j <= m) Wp[OM(m) + j] = col[j];
            }

            float4* dst = (float4*)&Wtab_w[c * 36];
            #pragma unroll
            for (int i = 0; i < 9; ++i)
                dst[i] = make_float4(Wp[4*i], Wp[4*i+1], Wp[4*i+2], Wp[4*i+3]);
        }
    }
    __syncthreads();

    // ---- serial backward sweep ----
    Chunk A, B;
    float u, waccv = 0.0f;

    // prologue: chunk 255 fully, chunk 254 tokens
    A.tokv = toklds[2040 + l7];
    #pragma unroll
    for (int j = 0; j < 8; ++j) A.tk[j] = RLI(A.tokv, j);
    #pragma unroll
    for (int j = 0; j < 8; ++j) A.grow[j] = Gg[A.tk[j] * 64 + lane];
    {
        const float4* wsrc = (const float4*)&Wtab_w[255 * 36];
        #pragma unroll
        for (int i = 0; i < 9; ++i) {
            float4 v = wsrc[i];
            A.W[4*i] = v.x; A.W[4*i+1] = v.y; A.W[4*i+2] = v.z; A.W[4*i+3] = v.w;
        }
    }
    B.tokv = toklds[2032 + l7];
    u = Gg[A.tk[7] * 64 + lane];     // query token = position 2047

    auto body = [&](Chunk& cur, Chunk& nxt, int c) {
        // gather t_j = u[tok_j] (lane j holds index tok_{8c+j})
        float bp = __shfl(u, cur.tokv, 64);

        // prefetch chunk c-1 (independent of the u-chain)
        const int cm1 = (c > 0) ? c - 1 : 0;
        const int cm2 = (c > 1) ? c - 2 : 0;
        #pragma unroll
        for (int j = 0; j < 8; ++j) nxt.tk[j] = RLI(nxt.tokv, j);
        #pragma unroll
        for (int j = 0; j < 8; ++j) nxt.grow[j] = Gg[nxt.tk[j] * 64 + lane];
        {
            const float4* wsrc = (const float4*)&Wtab_w[cm1 * 36];
            #pragma unroll
            for (int i = 0; i < 9; ++i) {
                float4 v = wsrc[i];
                nxt.W[4*i] = v.x; nxt.W[4*i+1] = v.y; nxt.W[4*i+2] = v.z; nxt.W[4*i+3] = v.w;
            }
        }
        int tokv2 = toklds[cm2 * 8 + l7];

        float t0 = RLF(bp, 0), t1 = RLF(bp, 1), t2 = RLF(bp, 2), t3 = RLF(bp, 3);
        float t4 = RLF(bp, 4), t5 = RLF(bp, 5), t6 = RLF(bp, 6), t7 = RLF(bp, 7);

        // s = W t  (36 independent FMAs, depth <= 4)
        const float* W = cur.W;
        float s7 = W[35] * t7;
        float s6 = fmaf(W[27], t6, W[34] * t7);
        float s5 = fmaf(W[20], t5, W[26] * t6) + W[33] * t7;
        float s4 = fmaf(W[14], t4, W[19] * t5) + fmaf(W[25], t6, W[32] * t7);
        float s3 = fmaf(W[9],  t3, W[13] * t4) + fmaf(W[18], t5, fmaf(W[24], t6, W[31] * t7));
        float s2 = fmaf(W[5],  t2, W[8]  * t3) + fmaf(W[12], t4, W[17] * t5) + fmaf(W[23], t6, W[30] * t7);
        float s1 = fmaf(W[2],  t1, W[4]  * t2) + fmaf(W[7],  t3, W[11] * t4) + fmaf(W[16], t5, fmaf(W[22], t6, W[29] * t7));
        float s0 = fmaf(W[0],  t0, W[1]  * t1) + fmaf(W[3],  t2, W[6]  * t3) + fmaf(W[10], t4, W[15] * t5) + fmaf(W[21], t6, W[28] * t7);

        // u[a] -= sum_j s_j * G[tok_j][a]
        float dA = fmaf(cur.grow[0], s0, fmaf(cur.grow[1], s1, fmaf(cur.grow[2], s2, cur.grow[3] * s3)));
        float dB = fmaf(cur.grow[4], s4, fmaf(cur.grow[5], s5, fmaf(cur.grow[6], s6, cur.grow[7] * s7)));
        u -= (dA + dB);

        // wacc[tok_j] += s_j  (lane = token)
        waccv += (lane == cur.tk[0]) ? s0 : 0.0f;
        waccv += (lane == cur.tk[1]) ? s1 : 0.0f;
        waccv += (lane == cur.tk[2]) ? s2 : 0.0f;
        waccv += (lane == cur.tk[3]) ? s3 : 0.0f;
        waccv += (lane == cur.tk[4]) ? s4 : 0.0f;
        waccv += (lane == cur.tk[5]) ? s5 : 0.0f;
        waccv += (lane == cur.tk[6]) ? s6 : 0.0f;
        waccv += (lane == cur.tk[7]) ? s7 : 0.0f;

        cur.tokv = tokv2;   // retire cur; its tokv becomes chunk c-2's lane tokens
    };

    for (int c = 255; c >= 1; c -= 2) {
        body(A, B, c);
        body(B, A, c - 1);
    }

    wacc_s[w][lane] = waccv;
    __syncthreads();

    // r[w2][rho] = sum_tok wacc[w2][tok] * v[w2][tok][rho]  (v from global ws)
    if (tid < 64) {
        const int w2  = tid >> 5;
        const int rho = tid & 31;
        const float* vv = ws + 4096 + w2 * 2048;
        const float* wa = &wacc_s[w2][0];
        float acc = 0.0f;
        #pragma unroll 8
        for (int tok = 0; tok < 64; ++tok) acc = fmaf(wa[tok], vv[tok * 32 + rho], acc);
        r_s[tid] = acc;
    }
    __syncthreads();

    // out = (r @ Wrp.T + brp) @ Wo.T + bo
    if (tid < 64) {
        float acc = brp[tid];
        #pragma unroll 8
        for (int m = 0; m < 64; ++m) acc = fmaf(Wrp[tid * 64 + m], r_s[m], acc);
        t1_s[tid] = acc;
    }
    __syncthreads();
    if (tid < 64) {
        float acc = bo[tid];
        #pragma unroll 8
        for (int m = 0; m < 64; ++m) acc = fmaf(Wo[tid * 64 + m], t1_s[m], acc);
        out[b * 64 + tid] = acc;
    }
}

extern "C" void kernel_launch(void* const* d_in, const int* in_sizes, int n_in,
                              void* d_out, int out_size, void* d_ws, size_t ws_size,
                              hipStream_t stream)
{
    const int*   seq   = (const int*)  d_in[0];
    const float* embed = (const float*)d_in[1];
    const float* W1    = (const float*)d_in[2];
    const float* b1    = (const float*)d_in[3];
    const float* W2    = (const float*)d_in[4];
    const float* b2    = (const float*)d_in[5];
    const float* ln_g  = (const float*)d_in[6];
    const float* ln_b  = (const float*)d_in[7];
    const float* Ws    = (const float*)d_in[8];
    const float* bs    = (const float*)d_in[9];
    const float* We    = (const float*)d_in[10];
    const float* be    = (const float*)d_in[11];
    const float* Wrp   = (const float*)d_in[12];
    const float* brp   = (const float*)d_in[13];
    const float* Wo    = (const float*)d_in[14];
    const float* bo    = (const float*)d_in[15];
    float* ws  = (float*)d_ws;
    float* out = (float*)d_out;

    hipLaunchKernelGGL(vocab_kernel, dim3(VOCAB), dim3(64), 0, stream,
                       embed, W1, b1, W2, b2, ln_g, ln_b, Ws, bs, We, be, ws);
    hipLaunchKernelGGL(gram_kernel, dim3(2), dim3(256), 0, stream, ws);
    hipLaunchKernelGGL(scan_kernel, dim3(BATCH), dim3(128), 0, stream,
                       seq, ws, Wrp, brp, Wo, bo, out);
}